// Round 6
// baseline (149.348 us; speedup 1.0000x reference)
//
#include <hip/hip_runtime.h>
#include <stdint.h>

#define NPIX     65536
#define NTHREADS 1024
#define NSLICES  512
#define NFEAT    18
#define EMB      256
#define THRESH_RANK 52428u  // 0.8f*(65536-1) == 52428.0 exactly in f32 => fr == 0
#define NB       24         // l2 histogram slots (24*256*4B = 24 KB LDS)
#define IVMAX    4          // max bin intervals per Pass B round
#define EPT4     16         // float4 iterations per thread

// ---------- sortable key mapping (monotonic with float order) ----------
__device__ __forceinline__ uint32_t f2key(float f) {
  uint32_t u = __float_as_uint(f);
  return u ^ ((uint32_t)((int32_t)u >> 31) | 0x80000000u);
}
__device__ __forceinline__ float key2f(uint32_t k) {
  uint32_t u = (k & 0x80000000u) ? (k ^ 0x80000000u) : ~k;
  return __uint_as_float(u);
}

// block-wide inclusive prefix over 2048 bins (Pass A only)
__device__ void scan2048(uint32_t* H, uint32_t* Wsum) {
  int tid = threadIdx.x, lane = tid & 63, wid = tid >> 6;
  uint32_t a1 = H[2 * tid + 1];
  uint32_t v = H[2 * tid] + a1;
  for (int d = 1; d < 64; d <<= 1) {
    uint32_t t = __shfl_up(v, d);
    if (lane >= d) v += t;
  }
  if (lane == 63) Wsum[wid] = v;
  __syncthreads();
  uint32_t woff = 0;
  for (int w = 0; w < wid; ++w) woff += Wsum[w];
  v += woff;
  H[2 * tid + 1] = v;
  H[2 * tid]     = v - a1;
  __syncthreads();
}

// wave-synchronous find: smallest b with C[b] > r (inclusive prefix, 2048)
__device__ __forceinline__ int wfind2048(const uint32_t* C, uint32_t r, int lane) {
  unsigned long long m = __ballot(C[lane * 32 + 31] > r);
  int chunk = __builtin_ctzll(m);
  unsigned long long m2 = __ballot((lane < 32) && (C[chunk * 32 + lane] > r));
  int off = __builtin_ctzll(m2);
  return chunk * 32 + off;
}
// same over 256-entry inclusive prefix
__device__ __forceinline__ int wfind256(const uint32_t* P, uint32_t r, int lane) {
  unsigned long long m = __ballot(P[lane * 4 + 3] > r);
  int chunk = __builtin_ctzll(m);
  int off = 0;
  while (off < 3 && P[chunk * 4 + off] <= r) ++off;
  return chunk * 4 + off;
}
// wave-synchronous in-place inclusive scan of 256 bins
__device__ __forceinline__ void wscan256(uint32_t* H, int lane) {
  uint32_t h0 = H[lane * 4 + 0], h1 = H[lane * 4 + 1];
  uint32_t h2 = H[lane * 4 + 2], h3 = H[lane * 4 + 3];
  uint32_t s = h0 + h1 + h2 + h3, inc = s;
  for (int d = 1; d < 64; d <<= 1) { uint32_t o = __shfl_up(inc, d); if (lane >= d) inc += o; }
  uint32_t base = inc - s;
  H[lane * 4 + 0] = base + h0;
  H[lane * 4 + 1] = base + h0 + h1;
  H[lane * 4 + 2] = base + h0 + h1 + h2;
  H[lane * 4 + 3] = base + s;
}

// bin -> slot via interval table (wave-uniform LDS reads)
__device__ __forceinline__ int slotOf(uint32_t b, const uint32_t* ivLo, const uint32_t* ivHi,
                                      const uint32_t* ivS0, int niv) {
  for (int j = 0; j < niv; ++j)
    if (b >= ivLo[j] && b <= ivHi[j]) return (int)(ivS0[j] + b - ivLo[j]);
  return -1;
}

// lane0-scalar: merge ≤6 bins into ≤IVMAX intervals, assign slots
__device__ void plan_from_bins(int m, const uint32_t* pbin,
                               uint32_t* ivLo, uint32_t* ivHi, uint32_t* ivS0,
                               int* pniv, int* pnslots) {
  uint32_t b[6];
  for (int i = 0; i < m; ++i) b[i] = pbin[i];
  for (int i = 1; i < m; ++i) {
    uint32_t x = b[i]; int j = i - 1;
    while (j >= 0 && b[j] > x) { b[j + 1] = b[j]; --j; }
    b[j + 1] = x;
  }
  int niv = 0; uint32_t s0 = 0; int i = 0;
  while (i < m && niv < IVMAX) {
    uint32_t lo = b[i], hi = b[i]; ++i;
    while (i < m && b[i] <= hi + 1) { hi = max(hi, b[i]); ++i; }
    ivLo[niv] = lo; ivHi[niv] = hi; ivS0[niv] = s0;
    s0 += hi - lo + 1; ++niv;
  }
  for (int j = niv; j < IVMAX; ++j) { ivLo[j] = 0xFFFFu; ivHi[j] = 0u; ivS0[j] = 0u; }
  *pniv = niv; *pnslots = (int)s0;
}

__global__ __launch_bounds__(NTHREADS) void feat_kernel(const float* __restrict__ vol,
                                                        float* __restrict__ feats) {
  __shared__ uint32_t HC1[2048];        // l1 histogram -> inclusive prefix C1
  __shared__ uint32_t L2H[NB * 256];    // per-candidate-bin 256-bin l2 hists -> prefixes
  __shared__ uint32_t Wsum[16];
  __shared__ double   tmpD9[16 * 9];
  __shared__ double   s_red[9];
  __shared__ uint32_t H16[16 * 16];     // per-wave privatized entropy histogram
  __shared__ uint32_t smaxkey;
  __shared__ uint32_t s_ivLo[IVMAX], s_ivHi[IVMAX], s_ivS0[IVMAX];
  __shared__ int      s_niv, s_nslots;
  __shared__ float    s_thresh;
  __shared__ uint32_t s_cnlt;
  __shared__ float    s_qA[3], s_qB[3], s_qfr[3];
  __shared__ int      s_qdup[3];
  __shared__ uint32_t s_prank[6], s_pbin[6];
  __shared__ uint8_t  s_ptag[6];
  __shared__ int      s_npend;

  const int tid  = threadIdx.x;
  const int lane = tid & 63;
  const int wid  = tid >> 6;
  const float*  sl  = vol + (size_t)blockIdx.x * NPIX;
  const float4* sl4 = (const float4*)sl;

  // ---- Pass A: l1 histogram (key>>21) + global max ----
  HC1[2 * tid] = 0; HC1[2 * tid + 1] = 0;
  if (tid == 0) smaxkey = 0u;
  if (tid < 256) H16[tid] = 0u;
  __syncthreads();
  uint32_t mk = 0u;
#pragma unroll 4
  for (int t = 0; t < EPT4; ++t) {
    float4 f = sl4[tid + t * NTHREADS];
    uint32_t k0 = f2key(f.x), k1 = f2key(f.y), k2 = f2key(f.z), k3 = f2key(f.w);
    mk = max(mk, max(max(k0, k1), max(k2, k3)));
    atomicAdd(&HC1[k0 >> 21], 1u);
    atomicAdd(&HC1[k1 >> 21], 1u);
    atomicAdd(&HC1[k2 >> 21], 1u);
    atomicAdd(&HC1[k3 >> 21], 1u);
  }
  for (int d = 32; d > 0; d >>= 1) { uint32_t o = __shfl_down(mk, d); mk = max(mk, o); }
  if (lane == 0) atomicMax(&smaxkey, mk);
  __syncthreads();
  scan2048(HC1, Wsum);   // HC1 is now C1 (trailing barrier inside)

  // ---- round-1 planning (wave 0; lane 0 writes) ----
  if (tid < 64) {
    int b1t = wfind2048(HC1, THRESH_RANK, lane);
    uint32_t clo  = b1t ? HC1[b1t - 1] : 0u;
    uint32_t cmax = min(THRESH_RANK, HC1[b1t] - 1u);
    uint32_t rl[4], rh[4];
    rl[0] = (uint32_t)b1t; rh[0] = (uint32_t)b1t;   // threshold bin (as bin range)
    const float pp[3] = {0.25f, 0.5f, 0.75f};
#pragma unroll
    for (int qi = 0; qi < 3; ++qi) {
      float p = pp[qi];
      uint32_t rlo = clo  + (uint32_t)(int)floorf(p * ((float)(NPIX - clo)  - 1.0f));
      uint32_t rhi = cmax + (uint32_t)(int)floorf(p * ((float)(NPIX - cmax) - 1.0f)) + 1u;
      if (rhi > NPIX - 1u) rhi = NPIX - 1u;
      if (rlo > rhi) rlo = rhi;
      uint32_t ba = (uint32_t)wfind2048(HC1, rlo, lane);
      uint32_t bb = (uint32_t)wfind2048(HC1, rhi, lane);
      if (bb > ba + 5u) bb = ba + 5u;      // cap 6 bins/range; retry covers clips
      rl[qi + 1] = ba; rh[qi + 1] = bb;
    }
    if (lane == 0) {
      for (int i = 1; i < 4; ++i) {
        uint32_t xl = rl[i], xh = rh[i]; int j = i - 1;
        while (j >= 0 && rl[j] > xl) { rl[j + 1] = rl[j]; rh[j + 1] = rh[j]; --j; }
        rl[j + 1] = xl; rh[j + 1] = xh;
      }
      int niv = 0; uint32_t s0 = 0; int i = 0;
      while (i < 4 && niv < IVMAX && s0 < NB) {
        uint32_t lo = rl[i], hi = rh[i]; ++i;
        while (i < 4 && rl[i] <= hi + 1u) { hi = max(hi, rh[i]); ++i; }
        uint32_t cnt = hi - lo + 1u;
        if (s0 + cnt > NB) { cnt = NB - s0; hi = lo + cnt - 1u; }
        s_ivLo[niv] = lo; s_ivHi[niv] = hi; s_ivS0[niv] = s0;
        s0 += cnt; ++niv;
      }
      for (int j = niv; j < IVMAX; ++j) { s_ivLo[j] = 0xFFFFu; s_ivHi[j] = 0u; s_ivS0[j] = 0u; }
      s_niv = niv; s_nslots = (int)s0;
    }
  }
  __syncthreads();

  // ================= Pass B (+ rare retry rounds) =================
  for (int round = 0; round < 4; ++round) {
    {
      int ns = s_nslots;
      for (int i = tid; i < ns * 256; i += NTHREADS) L2H[i] = 0u;
    }
    __syncthreads();
    // traversal: interval-filtered l2 histogram build
    {
      uint32_t lo0 = s_ivLo[0], hi0 = s_ivHi[0], s00 = s_ivS0[0];
      uint32_t lo1 = s_ivLo[1], hi1 = s_ivHi[1], s01 = s_ivS0[1];
      uint32_t lo2 = s_ivLo[2], hi2 = s_ivHi[2], s02 = s_ivS0[2];
      uint32_t lo3 = s_ivLo[3], hi3 = s_ivHi[3], s03 = s_ivS0[3];
#pragma unroll 4
      for (int t = 0; t < EPT4; ++t) {
        float4 f = sl4[tid + t * NTHREADS];
#define PB(vv)                                                                  \
        { uint32_t k = f2key(vv); uint32_t b = k >> 21; uint32_t l2 = (k >> 13) & 255u; \
          if      (b >= lo0 && b <= hi0) atomicAdd(&L2H[(s00 + b - lo0) * 256 + l2], 1u); \
          else if (b >= lo1 && b <= hi1) atomicAdd(&L2H[(s01 + b - lo1) * 256 + l2], 1u); \
          else if (b >= lo2 && b <= hi2) atomicAdd(&L2H[(s02 + b - lo2) * 256 + l2], 1u); \
          else if (b >= lo3 && b <= hi3) atomicAdd(&L2H[(s03 + b - lo3) * 256 + l2], 1u); }
        PB(f.x) PB(f.y) PB(f.z) PB(f.w)
#undef PB
      }
    }
    __syncthreads();
    {
      int ns = s_nslots;
      for (int s = wid; s < ns; s += 16) wscan256(&L2H[s * 256], lane);
    }
    __syncthreads();

    // ---- resolve on wave 0 ----
    if (tid < 64) {
      int niv = s_niv;
      if (round == 0) {
        int b1t = wfind2048(HC1, THRESH_RANK, lane);
        uint32_t below = b1t ? HC1[b1t - 1] : 0u;
        int sl_ = slotOf((uint32_t)b1t, s_ivLo, s_ivHi, s_ivS0, niv);
        const uint32_t* P = &L2H[sl_ * 256];
        int b2 = wfind256(P, THRESH_RANK - below, lane);
        uint32_t cnlt = below + (b2 ? P[b2 - 1] : 0u);
        float th = key2f(((uint32_t)b1t << 21) | ((uint32_t)b2 << 13));
        if (lane == 0) { s_thresh = th; s_cnlt = cnlt; }
        uint32_t n = NPIX - cnlt, t0 = cnlt;
        float nm1f = (float)n - 1.0f;
        int last = (int)nm1f;
        const float pp[3] = {0.25f, 0.5f, 0.75f};
        int np = 0;
        for (int qi = 0; qi < 3; ++qi) {
          float pos = pp[qi] * nm1f;
          float lof = floorf(pos);
          float fr = pos - lof;
          int lo_i = (int)lof;
          int hi_i = min(lo_i + 1, last);
          bool needB = (fr > 0.0f) && (hi_i != lo_i);
          if (lane == 0) { s_qfr[qi] = fr; s_qdup[qi] = needB ? 0 : 1; }
          {
            uint32_t r = t0 + (uint32_t)lo_i;
            int b = wfind2048(HC1, r, lane);
            uint32_t bw = b ? HC1[b - 1] : 0u;
            int sq = slotOf((uint32_t)b, s_ivLo, s_ivHi, s_ivS0, niv);
            if (sq >= 0) {
              const uint32_t* Pq = &L2H[sq * 256];
              int b2q = wfind256(Pq, r - bw, lane);
              float v = key2f(((uint32_t)b << 21) | ((uint32_t)b2q << 13));
              if (lane == 0) { s_qA[qi] = v; s_qB[qi] = v; }
            } else {
              if (lane == 0) { s_prank[np] = r; s_ptag[np] = (uint8_t)(qi * 2); s_pbin[np] = (uint32_t)b; }
              ++np;
            }
          }
          if (needB) {
            uint32_t r = t0 + (uint32_t)hi_i;
            int b = wfind2048(HC1, r, lane);
            uint32_t bw = b ? HC1[b - 1] : 0u;
            int sq = slotOf((uint32_t)b, s_ivLo, s_ivHi, s_ivS0, niv);
            if (sq >= 0) {
              const uint32_t* Pq = &L2H[sq * 256];
              int b2q = wfind256(Pq, r - bw, lane);
              float v = key2f(((uint32_t)b << 21) | ((uint32_t)b2q << 13));
              if (lane == 0) s_qB[qi] = v;
            } else {
              if (lane == 0) { s_prank[np] = r; s_ptag[np] = (uint8_t)(qi * 2 + 1); s_pbin[np] = (uint32_t)b; }
              ++np;
            }
          }
        }
        if (lane == 0) {
          s_npend = np;
          if (np > 0) plan_from_bins(np, s_pbin, s_ivLo, s_ivHi, s_ivS0, &s_niv, &s_nslots);
        }
      } else {
        int np = s_npend, newnp = 0;
        for (int i = 0; i < np; ++i) {
          uint32_t r = s_prank[i];
          int tg = s_ptag[i];
          int b = wfind2048(HC1, r, lane);
          uint32_t bw = b ? HC1[b - 1] : 0u;
          int sq = slotOf((uint32_t)b, s_ivLo, s_ivHi, s_ivS0, niv);
          if (sq >= 0) {
            const uint32_t* Pq = &L2H[sq * 256];
            int b2q = wfind256(Pq, r - bw, lane);
            float v = key2f(((uint32_t)b << 21) | ((uint32_t)b2q << 13));
            if (lane == 0) { if (tg & 1) s_qB[tg >> 1] = v; else s_qA[tg >> 1] = v; }
          } else {
            if (lane == 0) { s_prank[newnp] = r; s_ptag[newnp] = (uint8_t)tg; s_pbin[newnp] = (uint32_t)b; }
            ++newnp;
          }
        }
        if (lane == 0) {
          s_npend = newnp;
          if (newnp > 0) plan_from_bins(newnp, s_pbin, s_ivLo, s_ivHi, s_ivS0, &s_niv, &s_nslots);
        }
      }
    }
    __syncthreads();
    if (s_npend == 0) break;
    __syncthreads();
  }

  const float thresh = s_thresh;
  const uint32_t n = NPIX - s_cnlt;
  const float vmax  = key2f(smaxkey);
  const float vminf = thresh;

  // ---- Pass D: row-streaming stencil (wave owns 16 rows, lane owns 4 cols) ----
  float rng = vmax - vminf;
  float denomf = (rng > 0.0f) ? rng : 1.0f;
  float sc16 = 16.0f / denomf;
  float sxl = 0, sx2l = 0, sx3l = 0, sx4l = 0, sabl = 0, sgl = 0, sg2l = 0;
  uint32_t syi = 0, sxi = 0;
  {
    const int y0 = wid * 16;
    float4 cur = sl4[y0 * 64 + lane];
    float4 up  = (y0 > 0) ? sl4[(y0 - 1) * 64 + lane] : cur;
    float4 dn  = sl4[(y0 + 1) * 64 + lane];   // y0+1 <= 241 always valid
#pragma unroll
    for (int r = 0; r < 16; ++r) {
      const int y = y0 + r;
      float4 nx = (y + 2 <= 255) ? sl4[(y + 2) * 64 + lane] : dn;
      float lf = __shfl_up(cur.w, 1);
      float rt = __shfl_down(cur.x, 1);
      // vertical gradient (wave-uniform y branches)
      float gy0, gy1, gy2, gy3;
      if (y == 0)        { gy0 = dn.x - cur.x; gy1 = dn.y - cur.y; gy2 = dn.z - cur.z; gy3 = dn.w - cur.w; }
      else if (y == 255) { gy0 = cur.x - up.x; gy1 = cur.y - up.y; gy2 = cur.z - up.z; gy3 = cur.w - up.w; }
      else { gy0 = 0.5f * (dn.x - up.x); gy1 = 0.5f * (dn.y - up.y);
             gy2 = 0.5f * (dn.z - up.z); gy3 = 0.5f * (dn.w - up.w); }
      // horizontal gradient (lane-edge selects)
      float gx0 = (lane == 0)  ? (cur.y - cur.x) : 0.5f * (cur.y - lf);
      float gx1 = 0.5f * (cur.z - cur.x);
      float gx2 = 0.5f * (cur.w - cur.y);
      float gx3 = (lane == 63) ? (cur.w - cur.z) : 0.5f * (rt - cur.z);
#define DOC(vc, gyc, gxc, xc)                                                  \
      { bool mc = (vc) >= thresh;                                              \
        float mm = mc ? 1.0f : 0.0f;                                           \
        float gm = sqrtf((gyc) * (gyc) + (gxc) * (gxc));                       \
        sgl  = fmaf(mm, gm, sgl);                                              \
        sg2l = fmaf(mm * gm, gm, sg2l);                                        \
        float v2 = (vc) * (vc);                                                \
        sxl  = fmaf(mm, (vc), sxl);                                            \
        sx2l = fmaf(mm, v2, sx2l);                                             \
        sx3l = fmaf(mm * v2, (vc), sx3l);                                      \
        sx4l = fmaf(mm * v2, v2, sx4l);                                        \
        sabl = fmaf(mm, fabsf(vc), sabl);                                      \
        syi += mc ? (uint32_t)y : 0u;                                          \
        sxi += mc ? (uint32_t)((lane << 2) + (xc)) : 0u;                       \
        if (mc) {                                                              \
          float bf = floorf(((vc) - vminf) * sc16);                            \
          int bin = (int)bf; bin = bin < 0 ? 0 : (bin > 15 ? 15 : bin);        \
          atomicAdd(&H16[(wid << 4) + bin], 1u);                               \
        } }
      DOC(cur.x, gy0, gx0, 0)
      DOC(cur.y, gy1, gx1, 1)
      DOC(cur.z, gy2, gx2, 2)
      DOC(cur.w, gy3, gx3, 3)
#undef DOC
      up = cur; cur = dn; dn = nx;
    }
  }

  // ---- fused 9-way f64 reduction ----
  double a[9] = {(double)sxl, (double)sx2l, (double)sx3l, (double)sx4l,
                 (double)sabl, (double)sgl, (double)sg2l, (double)syi, (double)sxi};
#pragma unroll
  for (int k = 0; k < 9; ++k)
    for (int d = 32; d > 0; d >>= 1) a[k] += __shfl_down(a[k], d);
  if (lane == 0) {
#pragma unroll
    for (int k = 0; k < 9; ++k) tmpD9[wid * 9 + k] = a[k];
  }
  __syncthreads();
  if (tid < 64) {
    double r0 = 0, r1 = 0, r2 = 0, r3 = 0, r4 = 0, r5 = 0, r6 = 0, r7 = 0, r8 = 0;
    if (lane < 16) {
      r0 = tmpD9[lane * 9 + 0]; r1 = tmpD9[lane * 9 + 1]; r2 = tmpD9[lane * 9 + 2];
      r3 = tmpD9[lane * 9 + 3]; r4 = tmpD9[lane * 9 + 4]; r5 = tmpD9[lane * 9 + 5];
      r6 = tmpD9[lane * 9 + 6]; r7 = tmpD9[lane * 9 + 7]; r8 = tmpD9[lane * 9 + 8];
    }
    for (int d = 8; d > 0; d >>= 1) {
      r0 += __shfl_down(r0, d); r1 += __shfl_down(r1, d); r2 += __shfl_down(r2, d);
      r3 += __shfl_down(r3, d); r4 += __shfl_down(r4, d); r5 += __shfl_down(r5, d);
      r6 += __shfl_down(r6, d); r7 += __shfl_down(r7, d); r8 += __shfl_down(r8, d);
    }
    if (lane == 0) {
      s_red[0] = r0; s_red[1] = r1; s_red[2] = r2; s_red[3] = r3; s_red[4] = r4;
      s_red[5] = r5; s_red[6] = r6; s_red[7] = r7; s_red[8] = r8;
    }
  }
  __syncthreads();

  // ---- finalize features (thread 0) ----
  if (tid == 0) {
    double sx = s_red[0], sx2 = s_red[1], sx3 = s_red[2], sx4 = s_red[3];
    double sab = s_red[4], sg = s_red[5], sg2 = s_red[6], syid = s_red[7], sxid = s_red[8];
    double dn = (double)n;
    double mean = sx / dn;
    double M2 = sx2 - sx * sx / dn;
    double std_ = sqrt(M2 / dn);
    double se = fmax(std_, 1e-6);
    double S3 = sx3 - 3.0 * mean * sx2 + 2.0 * dn * mean * mean * mean;
    double S4 = sx4 - 4.0 * mean * sx3 + 6.0 * mean * mean * sx2
                - 3.0 * dn * mean * mean * mean * mean;
    double skew = (S3 / dn) / (se * se * se);
    skew = fmin(fmax(skew, -50.0), 50.0);
    double kurt = (S4 / dn) / (se * se * se * se);
    kurt = fmin(fmax(kurt, 0.0), 100.0);
    double msq = sx2 / dn;
    double absmean = sab / dn;

    double ent = 0.0;
    double nden = fmax(dn, 1.0);
    for (int bi = 0; bi < 16; ++bi) {
      uint32_t hb = 0;
#pragma unroll
      for (int w = 0; w < 16; ++w) hb += H16[(w << 4) + bi];
      double p = fmax((double)hb / nden, 1e-6);
      ent -= p * log(p);
    }
    if (fabsf(vminf - vmax) <= 1e-8f + 1e-5f * fabsf(vmax)) ent = 0.0;

    double gmean = sg / dn;
    double gstd = sqrt(fmax(sg2 / dn - gmean * gmean, 0.0));
    double cy = (syid / dn) / 255.0;
    double cx = (sxid / dn) / 255.0;
    double frac = dn / (double)NPIX;

    float qv[3];
#pragma unroll
    for (int qi = 0; qi < 3; ++qi) {
      float A = s_qA[qi];
      float Bv = s_qdup[qi] ? A : s_qB[qi];
      float fr = s_qfr[qi];
      qv[qi] = A * (1.0f - fr) + Bv * fr;
    }

    float* fo = feats + (size_t)blockIdx.x * NFEAT;
    fo[0]  = (float)mean;  fo[1]  = (float)std_;  fo[2]  = vminf;       fo[3]  = vmax;
    fo[4]  = qv[0];        fo[5]  = qv[1];        fo[6]  = qv[2];       fo[7]  = (float)msq;
    fo[8]  = (float)ent;   fo[9]  = (float)skew;  fo[10] = (float)kurt; fo[11] = (float)frac;
    fo[12] = (float)gmean; fo[13] = (float)gstd;  fo[14] = (float)cy;   fo[15] = (float)cx;
    fo[16] = (float)frac;  fo[17] = (float)absmean;
  }
}

__global__ __launch_bounds__(EMB) void token_kernel(const float* __restrict__ feats,
                                                    const float* __restrict__ W,
                                                    const float* __restrict__ b,
                                                    const float* __restrict__ gamma,
                                                    const float* __restrict__ beta,
                                                    float* __restrict__ out,
                                                    float* __restrict__ maskout) {
  __shared__ float f[NFEAT];
  __shared__ float red[4];
  int s = blockIdx.x, e = threadIdx.x;
  if (e < NFEAT) f[e] = feats[(size_t)s * NFEAT + e];
  __syncthreads();
  float acc = b[e];
#pragma unroll
  for (int k = 0; k < NFEAT; ++k) acc += f[k] * W[k * EMB + e];
  int lane = e & 63, wd = e >> 6;
  float sum = acc;
  for (int d = 32; d > 0; d >>= 1) sum += __shfl_down(sum, d);
  if (lane == 0) red[wd] = sum;
  __syncthreads();
  float mu = (red[0] + red[1] + red[2] + red[3]) * (1.0f / EMB);
  float c = acc - mu;
  float s2 = c * c;
  for (int d = 32; d > 0; d >>= 1) s2 += __shfl_down(s2, d);
  __syncthreads();
  if (lane == 0) red[wd] = s2;
  __syncthreads();
  float var = (red[0] + red[1] + red[2] + red[3]) * (1.0f / EMB);
  float o = c / sqrtf(var + 1e-5f) * gamma[e] + beta[e];
  out[(size_t)s * EMB + e] = o;
  if (e == 0) maskout[s] = 0.0f;
}

extern "C" void kernel_launch(void* const* d_in, const int* in_sizes, int n_in,
                              void* d_out, int out_size, void* d_ws, size_t ws_size,
                              hipStream_t stream) {
  const float* vol   = (const float*)d_in[0];
  const float* W     = (const float*)d_in[1];
  const float* b     = (const float*)d_in[2];
  const float* gamma = (const float*)d_in[3];
  const float* beta  = (const float*)d_in[4];
  float* out = (float*)d_out;
  float* feats = (float*)d_ws;

  feat_kernel<<<NSLICES, NTHREADS, 0, stream>>>(vol, feats);
  token_kernel<<<NSLICES, EMB, 0, stream>>>(feats, W, b, gamma, beta,
                                            out, out + (size_t)NSLICES * EMB);
}

// Round 7
// 107.256 us; speedup vs baseline: 1.3924x; 1.3924x over previous
//
#include <hip/hip_runtime.h>
#include <stdint.h>

#define NPIX     65536
#define NTHREADS 1024
#define NSLICES  512
#define NFEAT    18
#define EMB      256
#define THRESH_RANK 52428u  // 0.8f*(65536-1) == 52428.0 exactly in f32 => fr == 0
#define NB       24         // l2 histogram slots (24*256*4B = 24 KB LDS)
#define IVMAX    4          // max bin intervals per Pass B round
#define EPT4     16         // float4 iterations per thread

// ---------- sortable key mapping (monotonic with float order) ----------
__device__ __forceinline__ uint32_t f2key(float f) {
  uint32_t u = __float_as_uint(f);
  return u ^ ((uint32_t)((int32_t)u >> 31) | 0x80000000u);
}
__device__ __forceinline__ float key2f(uint32_t k) {
  uint32_t u = (k & 0x80000000u) ? (k ^ 0x80000000u) : ~k;
  return __uint_as_float(u);
}

// block-wide inclusive prefix over 2048 bins (Pass A only)
__device__ void scan2048(uint32_t* H, uint32_t* Wsum) {
  int tid = threadIdx.x, lane = tid & 63, wid = tid >> 6;
  uint32_t a1 = H[2 * tid + 1];
  uint32_t v = H[2 * tid] + a1;
  for (int d = 1; d < 64; d <<= 1) {
    uint32_t t = __shfl_up(v, d);
    if (lane >= d) v += t;
  }
  if (lane == 63) Wsum[wid] = v;
  __syncthreads();
  uint32_t woff = 0;
  for (int w = 0; w < wid; ++w) woff += Wsum[w];
  v += woff;
  H[2 * tid + 1] = v;
  H[2 * tid]     = v - a1;
  __syncthreads();
}

// wave-synchronous find: smallest b with C[b] > r (inclusive prefix, 2048)
__device__ __forceinline__ int wfind2048(const uint32_t* C, uint32_t r, int lane) {
  unsigned long long m = __ballot(C[lane * 32 + 31] > r);
  int chunk = __builtin_ctzll(m);
  unsigned long long m2 = __ballot((lane < 32) && (C[chunk * 32 + lane] > r));
  int off = __builtin_ctzll(m2);
  return chunk * 32 + off;
}
// same over 256-entry inclusive prefix
__device__ __forceinline__ int wfind256(const uint32_t* P, uint32_t r, int lane) {
  unsigned long long m = __ballot(P[lane * 4 + 3] > r);
  int chunk = __builtin_ctzll(m);
  int off = 0;
  while (off < 3 && P[chunk * 4 + off] <= r) ++off;
  return chunk * 4 + off;
}
// wave-synchronous in-place inclusive scan of 256 bins
__device__ __forceinline__ void wscan256(uint32_t* H, int lane) {
  uint32_t h0 = H[lane * 4 + 0], h1 = H[lane * 4 + 1];
  uint32_t h2 = H[lane * 4 + 2], h3 = H[lane * 4 + 3];
  uint32_t s = h0 + h1 + h2 + h3, inc = s;
  for (int d = 1; d < 64; d <<= 1) { uint32_t o = __shfl_up(inc, d); if (lane >= d) inc += o; }
  uint32_t base = inc - s;
  H[lane * 4 + 0] = base + h0;
  H[lane * 4 + 1] = base + h0 + h1;
  H[lane * 4 + 2] = base + h0 + h1 + h2;
  H[lane * 4 + 3] = base + s;
}

// bin -> slot via interval table (wave-uniform LDS reads)
__device__ __forceinline__ int slotOf(uint32_t b, const uint32_t* ivLo, const uint32_t* ivHi,
                                      const uint32_t* ivS0, int niv) {
  for (int j = 0; j < niv; ++j)
    if (b >= ivLo[j] && b <= ivHi[j]) return (int)(ivS0[j] + b - ivLo[j]);
  return -1;
}

// lane0-scalar: merge ≤6 bins into ≤IVMAX intervals, assign slots
__device__ void plan_from_bins(int m, const uint32_t* pbin,
                               uint32_t* ivLo, uint32_t* ivHi, uint32_t* ivS0,
                               int* pniv, int* pnslots) {
  uint32_t b[6];
  for (int i = 0; i < m; ++i) b[i] = pbin[i];
  for (int i = 1; i < m; ++i) {
    uint32_t x = b[i]; int j = i - 1;
    while (j >= 0 && b[j] > x) { b[j + 1] = b[j]; --j; }
    b[j + 1] = x;
  }
  int niv = 0; uint32_t s0 = 0; int i = 0;
  while (i < m && niv < IVMAX) {
    uint32_t lo = b[i], hi = b[i]; ++i;
    while (i < m && b[i] <= hi + 1) { hi = max(hi, b[i]); ++i; }
    ivLo[niv] = lo; ivHi[niv] = hi; ivS0[niv] = s0;
    s0 += hi - lo + 1; ++niv;
  }
  for (int j = niv; j < IVMAX; ++j) { ivLo[j] = 0xFFFFu; ivHi[j] = 0u; ivS0[j] = 0u; }
  *pniv = niv; *pnslots = (int)s0;
}

__global__ __launch_bounds__(NTHREADS) void feat_kernel(const float* __restrict__ vol,
                                                        float* __restrict__ feats) {
  __shared__ uint32_t HC1[2048];        // l1 histogram -> inclusive prefix C1
  __shared__ uint32_t L2H[NB * 256];    // per-candidate-bin 256-bin l2 hists -> prefixes
  __shared__ uint32_t Wsum[16];
  __shared__ double   tmpD9[16 * 9];
  __shared__ double   s_red[9];
  __shared__ uint32_t H16[16 * 16];     // per-wave privatized entropy histogram
  __shared__ uint32_t smaxkey;
  __shared__ uint32_t s_ivLo[IVMAX], s_ivHi[IVMAX], s_ivS0[IVMAX];
  __shared__ int      s_niv, s_nslots;
  __shared__ float    s_thresh;
  __shared__ uint32_t s_cnlt;
  __shared__ float    s_qA[3], s_qB[3], s_qfr[3];
  __shared__ int      s_qdup[3];
  __shared__ uint32_t s_prank[6], s_pbin[6];
  __shared__ uint8_t  s_ptag[6];
  __shared__ int      s_npend;

  const int tid  = threadIdx.x;
  const int lane = tid & 63;
  const int wid  = tid >> 6;
  const float*  sl  = vol + (size_t)blockIdx.x * NPIX;
  const float4* sl4 = (const float4*)sl;

  // ---- Pass A: l1 histogram (key>>21) + global max ----
  HC1[2 * tid] = 0; HC1[2 * tid + 1] = 0;
  if (tid == 0) smaxkey = 0u;
  if (tid < 256) H16[tid] = 0u;
  __syncthreads();
  uint32_t mk = 0u;
#pragma unroll 4
  for (int t = 0; t < EPT4; ++t) {
    float4 f = sl4[tid + t * NTHREADS];
    uint32_t k0 = f2key(f.x), k1 = f2key(f.y), k2 = f2key(f.z), k3 = f2key(f.w);
    mk = max(mk, max(max(k0, k1), max(k2, k3)));
    atomicAdd(&HC1[k0 >> 21], 1u);
    atomicAdd(&HC1[k1 >> 21], 1u);
    atomicAdd(&HC1[k2 >> 21], 1u);
    atomicAdd(&HC1[k3 >> 21], 1u);
  }
  for (int d = 32; d > 0; d >>= 1) { uint32_t o = __shfl_down(mk, d); mk = max(mk, o); }
  if (lane == 0) atomicMax(&smaxkey, mk);
  __syncthreads();
  scan2048(HC1, Wsum);   // HC1 is now C1 (trailing barrier inside)

  // ---- round-1 planning (wave 0; lane 0 writes) ----
  if (tid < 64) {
    int b1t = wfind2048(HC1, THRESH_RANK, lane);
    uint32_t clo  = b1t ? HC1[b1t - 1] : 0u;
    uint32_t cmax = min(THRESH_RANK, HC1[b1t] - 1u);
    uint32_t rl[4], rh[4];
    rl[0] = (uint32_t)b1t; rh[0] = (uint32_t)b1t;   // threshold bin (as bin range)
    const float pp[3] = {0.25f, 0.5f, 0.75f};
#pragma unroll
    for (int qi = 0; qi < 3; ++qi) {
      float p = pp[qi];
      uint32_t rlo = clo  + (uint32_t)(int)floorf(p * ((float)(NPIX - clo)  - 1.0f));
      uint32_t rhi = cmax + (uint32_t)(int)floorf(p * ((float)(NPIX - cmax) - 1.0f)) + 1u;
      if (rhi > NPIX - 1u) rhi = NPIX - 1u;
      if (rlo > rhi) rlo = rhi;
      uint32_t ba = (uint32_t)wfind2048(HC1, rlo, lane);
      uint32_t bb = (uint32_t)wfind2048(HC1, rhi, lane);
      if (bb > ba + 5u) bb = ba + 5u;      // cap 6 bins/range; retry covers clips
      rl[qi + 1] = ba; rh[qi + 1] = bb;
    }
    if (lane == 0) {
      for (int i = 1; i < 4; ++i) {
        uint32_t xl = rl[i], xh = rh[i]; int j = i - 1;
        while (j >= 0 && rl[j] > xl) { rl[j + 1] = rl[j]; rh[j + 1] = rh[j]; --j; }
        rl[j + 1] = xl; rh[j + 1] = xh;
      }
      int niv = 0; uint32_t s0 = 0; int i = 0;
      while (i < 4 && niv < IVMAX && s0 < NB) {
        uint32_t lo = rl[i], hi = rh[i]; ++i;
        while (i < 4 && rl[i] <= hi + 1u) { hi = max(hi, rh[i]); ++i; }
        uint32_t cnt = hi - lo + 1u;
        if (s0 + cnt > NB) { cnt = NB - s0; hi = lo + cnt - 1u; }
        s_ivLo[niv] = lo; s_ivHi[niv] = hi; s_ivS0[niv] = s0;
        s0 += cnt; ++niv;
      }
      for (int j = niv; j < IVMAX; ++j) { s_ivLo[j] = 0xFFFFu; s_ivHi[j] = 0u; s_ivS0[j] = 0u; }
      s_niv = niv; s_nslots = (int)s0;
    }
  }
  __syncthreads();

  // ================= Pass B (+ rare retry rounds) =================
  for (int round = 0; round < 4; ++round) {
    {
      int ns = s_nslots;
      for (int i = tid; i < ns * 256; i += NTHREADS) L2H[i] = 0u;
    }
    __syncthreads();
    // traversal: float-range filtered l2 histogram build.
    // bin test b in [lo,hi] on key top-11 bits == float in [key2f(lo<<21), key2f((hi+1)<<21))
    // (exact except -0.0 / NaN boundary cases, absent in this data). ~80% of
    // elements fail the FIRST compare (interval 0 starts at the 80th pctile bin),
    // skipping f2key entirely.
    {
      uint32_t lo0 = s_ivLo[0], hi0 = s_ivHi[0]; int s00 = (int)s_ivS0[0] - (int)lo0;
      uint32_t lo1 = s_ivLo[1], hi1 = s_ivHi[1]; int s01 = (int)s_ivS0[1] - (int)lo1;
      uint32_t lo2 = s_ivLo[2], hi2 = s_ivHi[2]; int s02 = (int)s_ivS0[2] - (int)lo2;
      uint32_t lo3 = s_ivLo[3], hi3 = s_ivHi[3]; int s03 = (int)s_ivS0[3] - (int)lo3;
      float fL0 = key2f(lo0 << 21);
      float fH0 = (hi0 >= 2047u) ? __builtin_inff() : key2f((hi0 + 1u) << 21);
      float fL1 = key2f(lo1 << 21);
      float fH1 = (hi1 >= 2047u) ? __builtin_inff() : key2f((hi1 + 1u) << 21);
      float fL2 = key2f(lo2 << 21);
      float fH2 = (hi2 >= 2047u) ? __builtin_inff() : key2f((hi2 + 1u) << 21);
      float fL3 = key2f(lo3 << 21);
      float fH3 = (hi3 >= 2047u) ? __builtin_inff() : key2f((hi3 + 1u) << 21);
#pragma unroll 4
      for (int t = 0; t < EPT4; ++t) {
        float4 f = sl4[tid + t * NTHREADS];
#define PB(vv)                                                                  \
        { float v_ = (vv); int sb = -0x40000000; \
          if      (v_ >= fL0 && v_ < fH0) sb = s00;                             \
          else if (v_ >= fL1 && v_ < fH1) sb = s01;                             \
          else if (v_ >= fL2 && v_ < fH2) sb = s02;                             \
          else if (v_ >= fL3 && v_ < fH3) sb = s03;                             \
          if (sb != -0x40000000) {                                              \
            uint32_t k = f2key(v_);                                             \
            atomicAdd(&L2H[(uint32_t)(sb + (int)(k >> 21)) * 256 + ((k >> 13) & 255u)], 1u); \
          } }
        PB(f.x) PB(f.y) PB(f.z) PB(f.w)
#undef PB
      }
    }
    __syncthreads();
    {
      int ns = s_nslots;
      for (int s = wid; s < ns; s += 16) wscan256(&L2H[s * 256], lane);
    }
    __syncthreads();

    // ---- resolve on wave 0 ----
    if (tid < 64) {
      int niv = s_niv;
      if (round == 0) {
        int b1t = wfind2048(HC1, THRESH_RANK, lane);
        uint32_t below = b1t ? HC1[b1t - 1] : 0u;
        int sl_ = slotOf((uint32_t)b1t, s_ivLo, s_ivHi, s_ivS0, niv);
        const uint32_t* P = &L2H[sl_ * 256];
        int b2 = wfind256(P, THRESH_RANK - below, lane);
        uint32_t cnlt = below + (b2 ? P[b2 - 1] : 0u);
        float th = key2f(((uint32_t)b1t << 21) | ((uint32_t)b2 << 13));
        if (lane == 0) { s_thresh = th; s_cnlt = cnlt; }
        uint32_t n = NPIX - cnlt, t0 = cnlt;
        float nm1f = (float)n - 1.0f;
        int last = (int)nm1f;
        const float pp[3] = {0.25f, 0.5f, 0.75f};
        int np = 0;
        for (int qi = 0; qi < 3; ++qi) {
          float pos = pp[qi] * nm1f;
          float lof = floorf(pos);
          float fr = pos - lof;
          int lo_i = (int)lof;
          int hi_i = min(lo_i + 1, last);
          bool needB = (fr > 0.0f) && (hi_i != lo_i);
          if (lane == 0) { s_qfr[qi] = fr; s_qdup[qi] = needB ? 0 : 1; }
          {
            uint32_t r = t0 + (uint32_t)lo_i;
            int b = wfind2048(HC1, r, lane);
            uint32_t bw = b ? HC1[b - 1] : 0u;
            int sq = slotOf((uint32_t)b, s_ivLo, s_ivHi, s_ivS0, niv);
            if (sq >= 0) {
              const uint32_t* Pq = &L2H[sq * 256];
              int b2q = wfind256(Pq, r - bw, lane);
              float v = key2f(((uint32_t)b << 21) | ((uint32_t)b2q << 13));
              if (lane == 0) { s_qA[qi] = v; s_qB[qi] = v; }
            } else {
              if (lane == 0) { s_prank[np] = r; s_ptag[np] = (uint8_t)(qi * 2); s_pbin[np] = (uint32_t)b; }
              ++np;
            }
          }
          if (needB) {
            uint32_t r = t0 + (uint32_t)hi_i;
            int b = wfind2048(HC1, r, lane);
            uint32_t bw = b ? HC1[b - 1] : 0u;
            int sq = slotOf((uint32_t)b, s_ivLo, s_ivHi, s_ivS0, niv);
            if (sq >= 0) {
              const uint32_t* Pq = &L2H[sq * 256];
              int b2q = wfind256(Pq, r - bw, lane);
              float v = key2f(((uint32_t)b << 21) | ((uint32_t)b2q << 13));
              if (lane == 0) s_qB[qi] = v;
            } else {
              if (lane == 0) { s_prank[np] = r; s_ptag[np] = (uint8_t)(qi * 2 + 1); s_pbin[np] = (uint32_t)b; }
              ++np;
            }
          }
        }
        if (lane == 0) {
          s_npend = np;
          if (np > 0) plan_from_bins(np, s_pbin, s_ivLo, s_ivHi, s_ivS0, &s_niv, &s_nslots);
        }
      } else {
        int np = s_npend, newnp = 0;
        for (int i = 0; i < np; ++i) {
          uint32_t r = s_prank[i];
          int tg = s_ptag[i];
          int b = wfind2048(HC1, r, lane);
          uint32_t bw = b ? HC1[b - 1] : 0u;
          int sq = slotOf((uint32_t)b, s_ivLo, s_ivHi, s_ivS0, niv);
          if (sq >= 0) {
            const uint32_t* Pq = &L2H[sq * 256];
            int b2q = wfind256(Pq, r - bw, lane);
            float v = key2f(((uint32_t)b << 21) | ((uint32_t)b2q << 13));
            if (lane == 0) { if (tg & 1) s_qB[tg >> 1] = v; else s_qA[tg >> 1] = v; }
          } else {
            if (lane == 0) { s_prank[newnp] = r; s_ptag[newnp] = (uint8_t)tg; s_pbin[newnp] = (uint32_t)b; }
            ++newnp;
          }
        }
        if (lane == 0) {
          s_npend = newnp;
          if (newnp > 0) plan_from_bins(newnp, s_pbin, s_ivLo, s_ivHi, s_ivS0, &s_niv, &s_nslots);
        }
      }
    }
    __syncthreads();
    if (s_npend == 0) break;
    __syncthreads();
  }

  const float thresh = s_thresh;
  const uint32_t n = NPIX - s_cnlt;
  const float vmax  = key2f(smaxkey);
  const float vminf = thresh;

  // ---- Pass D (fused): masked moments, |x|, centroid, hist16, gradient ----
  float rng = vmax - vminf;
  float denomf = (rng > 0.0f) ? rng : 1.0f;
  float sxl = 0, sx2l = 0, sx3l = 0, sx4l = 0, sabl = 0, sgl = 0, sg2l = 0;
  uint32_t syi = 0, sxi = 0;
#pragma unroll 4
  for (int t = 0; t < EPT4; ++t) {
    int i4 = tid + t * NTHREADS;
    float4 v = sl4[i4];
    bool m0 = v.x >= thresh, m1 = v.y >= thresh, m2 = v.z >= thresh, m3 = v.w >= thresh;
    if (m0 | m1 | m2 | m3) {
      int y = i4 >> 6, xb = (i4 & 63) << 2;
      float4 up = sl4[(y > 0)   ? (i4 - 64) : i4];
      float4 dn = sl4[(y < 255) ? (i4 + 64) : i4];
      float lf = (xb > 0)   ? sl[4 * i4 - 1] : 0.0f;
      float rt = (xb < 252) ? sl[4 * i4 + 4] : 0.0f;
#define DOC(mc, vc, upc, dnc, lv, rv, xc)                                      \
      if (mc) {                                                                \
        float gy = (y == 0) ? (dnc - vc) : ((y == 255) ? (vc - upc) : 0.5f * (dnc - upc)); \
        int xx = xb + (xc);                                                    \
        float gx = (xx == 0) ? (rv - vc) : ((xx == 255) ? (vc - lv) : 0.5f * (rv - lv));   \
        float gm = sqrtf(gy * gy + gx * gx);                                   \
        sgl += gm; sg2l += gm * gm;                                            \
        float v2 = vc * vc;                                                    \
        sxl += vc; sx2l += v2; sx3l += v2 * vc; sx4l += v2 * v2;               \
        sabl += fabsf(vc);                                                     \
        syi += (uint32_t)y; sxi += (uint32_t)xx;                               \
        float bf = floorf((vc - vminf) / denomf * 16.0f);                      \
        int bin = (int)bf; bin = bin < 0 ? 0 : (bin > 15 ? 15 : bin);          \
        atomicAdd(&H16[(wid << 4) + bin], 1u);                                 \
      }
      DOC(m0, v.x, up.x, dn.x, lf,  v.y, 0)
      DOC(m1, v.y, up.y, dn.y, v.x, v.z, 1)
      DOC(m2, v.z, up.z, dn.z, v.y, v.w, 2)
      DOC(m3, v.w, up.w, dn.w, v.z, rt,  3)
#undef DOC
    }
  }

  // ---- 9-way reduction: f32/u32 wave shuffles, f64 only across 16 waves ----
  {
    float af[7] = {sxl, sx2l, sx3l, sx4l, sabl, sgl, sg2l};
#pragma unroll
    for (int k = 0; k < 7; ++k)
      for (int d = 32; d > 0; d >>= 1) af[k] += __shfl_down(af[k], d);
    uint32_t au0 = syi, au1 = sxi;
    for (int d = 32; d > 0; d >>= 1) { au0 += __shfl_down(au0, d); au1 += __shfl_down(au1, d); }
    if (lane == 0) {
#pragma unroll
      for (int k = 0; k < 7; ++k) tmpD9[wid * 9 + k] = (double)af[k];
      tmpD9[wid * 9 + 7] = (double)au0;
      tmpD9[wid * 9 + 8] = (double)au1;
    }
  }
  __syncthreads();
  if (tid < 64) {
    double r0 = 0, r1 = 0, r2 = 0, r3 = 0, r4 = 0, r5 = 0, r6 = 0, r7 = 0, r8 = 0;
    if (lane < 16) {
      r0 = tmpD9[lane * 9 + 0]; r1 = tmpD9[lane * 9 + 1]; r2 = tmpD9[lane * 9 + 2];
      r3 = tmpD9[lane * 9 + 3]; r4 = tmpD9[lane * 9 + 4]; r5 = tmpD9[lane * 9 + 5];
      r6 = tmpD9[lane * 9 + 6]; r7 = tmpD9[lane * 9 + 7]; r8 = tmpD9[lane * 9 + 8];
    }
    for (int d = 8; d > 0; d >>= 1) {
      r0 += __shfl_down(r0, d); r1 += __shfl_down(r1, d); r2 += __shfl_down(r2, d);
      r3 += __shfl_down(r3, d); r4 += __shfl_down(r4, d); r5 += __shfl_down(r5, d);
      r6 += __shfl_down(r6, d); r7 += __shfl_down(r7, d); r8 += __shfl_down(r8, d);
    }
    if (lane == 0) {
      s_red[0] = r0; s_red[1] = r1; s_red[2] = r2; s_red[3] = r3; s_red[4] = r4;
      s_red[5] = r5; s_red[6] = r6; s_red[7] = r7; s_red[8] = r8;
    }
  }
  __syncthreads();

  // ---- finalize features (thread 0) ----
  if (tid == 0) {
    double sx = s_red[0], sx2 = s_red[1], sx3 = s_red[2], sx4 = s_red[3];
    double sab = s_red[4], sg = s_red[5], sg2 = s_red[6], syid = s_red[7], sxid = s_red[8];
    double dn = (double)n;
    double mean = sx / dn;
    double M2 = sx2 - sx * sx / dn;
    double std_ = sqrt(M2 / dn);
    double se = fmax(std_, 1e-6);
    double S3 = sx3 - 3.0 * mean * sx2 + 2.0 * dn * mean * mean * mean;
    double S4 = sx4 - 4.0 * mean * sx3 + 6.0 * mean * mean * sx2
                - 3.0 * dn * mean * mean * mean * mean;
    double skew = (S3 / dn) / (se * se * se);
    skew = fmin(fmax(skew, -50.0), 50.0);
    double kurt = (S4 / dn) / (se * se * se * se);
    kurt = fmin(fmax(kurt, 0.0), 100.0);
    double msq = sx2 / dn;
    double absmean = sab / dn;

    double ent = 0.0;
    double nden = fmax(dn, 1.0);
    for (int bi = 0; bi < 16; ++bi) {
      uint32_t hb = 0;
#pragma unroll
      for (int w = 0; w < 16; ++w) hb += H16[(w << 4) + bi];
      double p = fmax((double)hb / nden, 1e-6);
      ent -= p * log(p);
    }
    if (fabsf(vminf - vmax) <= 1e-8f + 1e-5f * fabsf(vmax)) ent = 0.0;

    double gmean = sg / dn;
    double gstd = sqrt(fmax(sg2 / dn - gmean * gmean, 0.0));
    double cy = (syid / dn) / 255.0;
    double cx = (sxid / dn) / 255.0;
    double frac = dn / (double)NPIX;

    float qv[3];
#pragma unroll
    for (int qi = 0; qi < 3; ++qi) {
      float A = s_qA[qi];
      float Bv = s_qdup[qi] ? A : s_qB[qi];
      float fr = s_qfr[qi];
      qv[qi] = A * (1.0f - fr) + Bv * fr;
    }

    float* fo = feats + (size_t)blockIdx.x * NFEAT;
    fo[0]  = (float)mean;  fo[1]  = (float)std_;  fo[2]  = vminf;       fo[3]  = vmax;
    fo[4]  = qv[0];        fo[5]  = qv[1];        fo[6]  = qv[2];       fo[7]  = (float)msq;
    fo[8]  = (float)ent;   fo[9]  = (float)skew;  fo[10] = (float)kurt; fo[11] = (float)frac;
    fo[12] = (float)gmean; fo[13] = (float)gstd;  fo[14] = (float)cy;   fo[15] = (float)cx;
    fo[16] = (float)frac;  fo[17] = (float)absmean;
  }
}

__global__ __launch_bounds__(EMB) void token_kernel(const float* __restrict__ feats,
                                                    const float* __restrict__ W,
                                                    const float* __restrict__ b,
                                                    const float* __restrict__ gamma,
                                                    const float* __restrict__ beta,
                                                    float* __restrict__ out,
                                                    float* __restrict__ maskout) {
  __shared__ float f[NFEAT];
  __shared__ float red[4];
  int s = blockIdx.x, e = threadIdx.x;
  if (e < NFEAT) f[e] = feats[(size_t)s * NFEAT + e];
  __syncthreads();
  float acc = b[e];
#pragma unroll
  for (int k = 0; k < NFEAT; ++k) acc += f[k] * W[k * EMB + e];
  int lane = e & 63, wd = e >> 6;
  float sum = acc;
  for (int d = 32; d > 0; d >>= 1) sum += __shfl_down(sum, d);
  if (lane == 0) red[wd] = sum;
  __syncthreads();
  float mu = (red[0] + red[1] + red[2] + red[3]) * (1.0f / EMB);
  float c = acc - mu;
  float s2 = c * c;
  for (int d = 32; d > 0; d >>= 1) s2 += __shfl_down(s2, d);
  __syncthreads();
  if (lane == 0) red[wd] = s2;
  __syncthreads();
  float var = (red[0] + red[1] + red[2] + red[3]) * (1.0f / EMB);
  float o = c / sqrtf(var + 1e-5f) * gamma[e] + beta[e];
  out[(size_t)s * EMB + e] = o;
  if (e == 0) maskout[s] = 0.0f;
}

extern "C" void kernel_launch(void* const* d_in, const int* in_sizes, int n_in,
                              void* d_out, int out_size, void* d_ws, size_t ws_size,
                              hipStream_t stream) {
  const float* vol   = (const float*)d_in[0];
  const float* W     = (const float*)d_in[1];
  const float* b     = (const float*)d_in[2];
  const float* gamma = (const float*)d_in[3];
  const float* beta  = (const float*)d_in[4];
  float* out = (float*)d_out;
  float* feats = (float*)d_ws;

  feat_kernel<<<NSLICES, NTHREADS, 0, stream>>>(vol, feats);
  token_kernel<<<NSLICES, EMB, 0, stream>>>(feats, W, b, gamma, beta,
                                            out, out + (size_t)NSLICES * EMB);
}

// Round 8
// 96.221 us; speedup vs baseline: 1.5521x; 1.1147x over previous
//
#include <hip/hip_runtime.h>
#include <stdint.h>

#define NPIX     65536
#define NTHREADS 1024
#define NSLICES  512
#define NFEAT    18
#define EMB      256
#define THRESH_RANK 52428u  // 0.8f*(65536-1) == 52428.0 exactly in f32 => fr == 0
#define NB       24         // l2 histogram slots (24*256*4B = 24 KB LDS)
#define IVMAX    4          // max bin intervals per Pass B round
#define EPT4     16         // float4 iterations per thread

// ---------- sortable key mapping (monotonic with float order) ----------
__device__ __forceinline__ uint32_t f2key(float f) {
  uint32_t u = __float_as_uint(f);
  return u ^ ((uint32_t)((int32_t)u >> 31) | 0x80000000u);
}
__device__ __forceinline__ float key2f(uint32_t k) {
  uint32_t u = (k & 0x80000000u) ? (k ^ 0x80000000u) : ~k;
  return __uint_as_float(u);
}

// block-wide inclusive prefix over 2048 bins (Pass A only)
__device__ void scan2048(uint32_t* H, uint32_t* Wsum) {
  int tid = threadIdx.x, lane = tid & 63, wid = tid >> 6;
  uint32_t a1 = H[2 * tid + 1];
  uint32_t v = H[2 * tid] + a1;
  for (int d = 1; d < 64; d <<= 1) {
    uint32_t t = __shfl_up(v, d);
    if (lane >= d) v += t;
  }
  if (lane == 63) Wsum[wid] = v;
  __syncthreads();
  uint32_t woff = 0;
  for (int w = 0; w < wid; ++w) woff += Wsum[w];
  v += woff;
  H[2 * tid + 1] = v;
  H[2 * tid]     = v - a1;
  __syncthreads();
}

// wave-synchronous find: smallest b with C[b] > r (inclusive prefix, 2048)
__device__ __forceinline__ int wfind2048(const uint32_t* C, uint32_t r, int lane) {
  unsigned long long m = __ballot(C[lane * 32 + 31] > r);
  int chunk = __builtin_ctzll(m);
  unsigned long long m2 = __ballot((lane < 32) && (C[chunk * 32 + lane] > r));
  int off = __builtin_ctzll(m2);
  return chunk * 32 + off;
}
// same over 256-entry inclusive prefix
__device__ __forceinline__ int wfind256(const uint32_t* P, uint32_t r, int lane) {
  unsigned long long m = __ballot(P[lane * 4 + 3] > r);
  int chunk = __builtin_ctzll(m);
  int off = 0;
  while (off < 3 && P[chunk * 4 + off] <= r) ++off;
  return chunk * 4 + off;
}
// wave-synchronous in-place inclusive scan of 256 bins
__device__ __forceinline__ void wscan256(uint32_t* H, int lane) {
  uint32_t h0 = H[lane * 4 + 0], h1 = H[lane * 4 + 1];
  uint32_t h2 = H[lane * 4 + 2], h3 = H[lane * 4 + 3];
  uint32_t s = h0 + h1 + h2 + h3, inc = s;
  for (int d = 1; d < 64; d <<= 1) { uint32_t o = __shfl_up(inc, d); if (lane >= d) inc += o; }
  uint32_t base = inc - s;
  H[lane * 4 + 0] = base + h0;
  H[lane * 4 + 1] = base + h0 + h1;
  H[lane * 4 + 2] = base + h0 + h1 + h2;
  H[lane * 4 + 3] = base + s;
}

// bin -> slot via interval table (wave-uniform LDS reads)
__device__ __forceinline__ int slotOf(uint32_t b, const uint32_t* ivLo, const uint32_t* ivHi,
                                      const uint32_t* ivS0, int niv) {
  for (int j = 0; j < niv; ++j)
    if (b >= ivLo[j] && b <= ivHi[j]) return (int)(ivS0[j] + b - ivLo[j]);
  return -1;
}

// lane0-scalar: merge ≤6 bins into ≤IVMAX intervals, assign slots
__device__ void plan_from_bins(int m, const uint32_t* pbin,
                               uint32_t* ivLo, uint32_t* ivHi, uint32_t* ivS0,
                               int* pniv, int* pnslots) {
  uint32_t b[6];
  for (int i = 0; i < m; ++i) b[i] = pbin[i];
  for (int i = 1; i < m; ++i) {
    uint32_t x = b[i]; int j = i - 1;
    while (j >= 0 && b[j] > x) { b[j + 1] = b[j]; --j; }
    b[j + 1] = x;
  }
  int niv = 0; uint32_t s0 = 0; int i = 0;
  while (i < m && niv < IVMAX) {
    uint32_t lo = b[i], hi = b[i]; ++i;
    while (i < m && b[i] <= hi + 1) { hi = max(hi, b[i]); ++i; }
    ivLo[niv] = lo; ivHi[niv] = hi; ivS0[niv] = s0;
    s0 += hi - lo + 1; ++niv;
  }
  for (int j = niv; j < IVMAX; ++j) { ivLo[j] = 0xFFFFu; ivHi[j] = 0u; ivS0[j] = 0u; }
  *pniv = niv; *pnslots = (int)s0;
}

__global__ __launch_bounds__(NTHREADS) void feat_kernel(const float* __restrict__ vol,
                                                        float* __restrict__ feats) {
  __shared__ uint32_t HC1[2048];        // l1 histogram -> inclusive prefix C1
  __shared__ uint32_t L2H[NB * 256];    // per-candidate-bin 256-bin l2 hists -> prefixes
  __shared__ uint32_t Wsum[16];
  __shared__ double   tmpD9[16 * 9];
  __shared__ double   s_red[9];
  __shared__ uint32_t H16[16 * 16];     // per-wave privatized entropy histogram
  __shared__ uint32_t smaxkey;
  __shared__ uint32_t s_ivLo[IVMAX], s_ivHi[IVMAX], s_ivS0[IVMAX];
  __shared__ int      s_niv, s_nslots;
  __shared__ float    s_thresh;
  __shared__ uint32_t s_cnlt;
  __shared__ float    s_qA[3], s_qB[3], s_qfr[3];
  __shared__ int      s_qdup[3];
  __shared__ uint32_t s_prank[6], s_pbin[6];
  __shared__ uint8_t  s_ptag[6];
  __shared__ int      s_npend;

  const int tid  = threadIdx.x;
  const int lane = tid & 63;
  const int wid  = tid >> 6;
  const float*  sl  = vol + (size_t)blockIdx.x * NPIX;
  const float4* sl4 = (const float4*)sl;

  // ---- Pass A: l1 histogram (key>>21) + global max ----
  HC1[2 * tid] = 0; HC1[2 * tid + 1] = 0;
  if (tid == 0) smaxkey = 0u;
  if (tid < 256) H16[tid] = 0u;
  __syncthreads();
  uint32_t mk = 0u;
#pragma unroll 4
  for (int t = 0; t < EPT4; ++t) {
    float4 f = sl4[tid + t * NTHREADS];
    uint32_t k0 = f2key(f.x), k1 = f2key(f.y), k2 = f2key(f.z), k3 = f2key(f.w);
    mk = max(mk, max(max(k0, k1), max(k2, k3)));
    atomicAdd(&HC1[k0 >> 21], 1u);
    atomicAdd(&HC1[k1 >> 21], 1u);
    atomicAdd(&HC1[k2 >> 21], 1u);
    atomicAdd(&HC1[k3 >> 21], 1u);
  }
  for (int d = 32; d > 0; d >>= 1) { uint32_t o = __shfl_down(mk, d); mk = max(mk, o); }
  if (lane == 0) atomicMax(&smaxkey, mk);
  __syncthreads();
  scan2048(HC1, Wsum);   // HC1 is now C1 (trailing barrier inside)

  // ---- round-1 planning (wave 0; lane 0 writes) ----
  if (tid < 64) {
    int b1t = wfind2048(HC1, THRESH_RANK, lane);
    uint32_t clo  = b1t ? HC1[b1t - 1] : 0u;
    uint32_t cmax = min(THRESH_RANK, HC1[b1t] - 1u);
    uint32_t rl[4], rh[4];
    rl[0] = (uint32_t)b1t; rh[0] = (uint32_t)b1t;   // threshold bin (as bin range)
    const float pp[3] = {0.25f, 0.5f, 0.75f};
#pragma unroll
    for (int qi = 0; qi < 3; ++qi) {
      float p = pp[qi];
      uint32_t rlo = clo  + (uint32_t)(int)floorf(p * ((float)(NPIX - clo)  - 1.0f));
      uint32_t rhi = cmax + (uint32_t)(int)floorf(p * ((float)(NPIX - cmax) - 1.0f)) + 1u;
      if (rhi > NPIX - 1u) rhi = NPIX - 1u;
      if (rlo > rhi) rlo = rhi;
      uint32_t ba = (uint32_t)wfind2048(HC1, rlo, lane);
      uint32_t bb = (uint32_t)wfind2048(HC1, rhi, lane);
      if (bb > ba + 5u) bb = ba + 5u;      // cap 6 bins/range; retry covers clips
      rl[qi + 1] = ba; rh[qi + 1] = bb;
    }
    if (lane == 0) {
      for (int i = 1; i < 4; ++i) {
        uint32_t xl = rl[i], xh = rh[i]; int j = i - 1;
        while (j >= 0 && rl[j] > xl) { rl[j + 1] = rl[j]; rh[j + 1] = rh[j]; --j; }
        rl[j + 1] = xl; rh[j + 1] = xh;
      }
      int niv = 0; uint32_t s0 = 0; int i = 0;
      while (i < 4 && niv < IVMAX && s0 < NB) {
        uint32_t lo = rl[i], hi = rh[i]; ++i;
        while (i < 4 && rl[i] <= hi + 1u) { hi = max(hi, rh[i]); ++i; }
        uint32_t cnt = hi - lo + 1u;
        if (s0 + cnt > NB) { cnt = NB - s0; hi = lo + cnt - 1u; }
        s_ivLo[niv] = lo; s_ivHi[niv] = hi; s_ivS0[niv] = s0;
        s0 += cnt; ++niv;
      }
      for (int j = niv; j < IVMAX; ++j) { s_ivLo[j] = 0xFFFFu; s_ivHi[j] = 0u; s_ivS0[j] = 0u; }
      s_niv = niv; s_nslots = (int)s0;
    }
  }
  __syncthreads();

  // ================= Pass B (+ rare retry rounds) =================
  for (int round = 0; round < 4; ++round) {
    {
      int ns = s_nslots;
      for (int i = tid; i < ns * 256; i += NTHREADS) L2H[i] = 0u;
    }
    __syncthreads();
    // traversal: float-range filtered l2 histogram build.
    // Intervals are sorted ascending and all candidate bins >= threshold bin,
    // so fL0 is the global minimum: a single compare rejects the ~80% below it.
    // bin b in [lo,hi] on key top-11 bits == float in [key2f(lo<<21), key2f((hi+1)<<21))
    // (exact except -0.0 / NaN boundary cases, absent in this data).
    {
      uint32_t lo0 = s_ivLo[0], hi0 = s_ivHi[0]; int s00 = (int)s_ivS0[0] - (int)lo0;
      uint32_t lo1 = s_ivLo[1], hi1 = s_ivHi[1]; int s01 = (int)s_ivS0[1] - (int)lo1;
      uint32_t lo2 = s_ivLo[2], hi2 = s_ivHi[2]; int s02 = (int)s_ivS0[2] - (int)lo2;
      uint32_t lo3 = s_ivLo[3], hi3 = s_ivHi[3]; int s03 = (int)s_ivS0[3] - (int)lo3;
      float fL0 = key2f(lo0 << 21);
      float fH0 = (hi0 >= 2047u) ? __builtin_inff() : key2f((hi0 + 1u) << 21);
      float fL1 = key2f(lo1 << 21);
      float fH1 = (hi1 >= 2047u) ? __builtin_inff() : key2f((hi1 + 1u) << 21);
      float fL2 = key2f(lo2 << 21);
      float fH2 = (hi2 >= 2047u) ? __builtin_inff() : key2f((hi2 + 1u) << 21);
      float fL3 = key2f(lo3 << 21);
      float fH3 = (hi3 >= 2047u) ? __builtin_inff() : key2f((hi3 + 1u) << 21);
#pragma unroll 4
      for (int t = 0; t < EPT4; ++t) {
        float4 f = sl4[tid + t * NTHREADS];
#define PB(vv)                                                                  \
        { float v_ = (vv);                                                      \
          if (v_ >= fL0) {                                                      \
            int sb = -0x40000000;                                               \
            if      (v_ < fH0)              sb = s00;                           \
            else if (v_ >= fL1 && v_ < fH1) sb = s01;                           \
            else if (v_ >= fL2 && v_ < fH2) sb = s02;                           \
            else if (v_ >= fL3 && v_ < fH3) sb = s03;                           \
            if (sb != -0x40000000) {                                            \
              uint32_t k = f2key(v_);                                           \
              atomicAdd(&L2H[(uint32_t)(sb + (int)(k >> 21)) * 256 + ((k >> 13) & 255u)], 1u); \
            } } }
        PB(f.x) PB(f.y) PB(f.z) PB(f.w)
#undef PB
      }
    }
    __syncthreads();
    {
      int ns = s_nslots;
      for (int s = wid; s < ns; s += 16) wscan256(&L2H[s * 256], lane);
    }
    __syncthreads();

    // ---- resolve on wave 0 ----
    if (tid < 64) {
      int niv = s_niv;
      if (round == 0) {
        int b1t = wfind2048(HC1, THRESH_RANK, lane);
        uint32_t below = b1t ? HC1[b1t - 1] : 0u;
        int sl_ = slotOf((uint32_t)b1t, s_ivLo, s_ivHi, s_ivS0, niv);
        const uint32_t* P = &L2H[sl_ * 256];
        int b2 = wfind256(P, THRESH_RANK - below, lane);
        uint32_t cnlt = below + (b2 ? P[b2 - 1] : 0u);
        float th = key2f(((uint32_t)b1t << 21) | ((uint32_t)b2 << 13));
        if (lane == 0) { s_thresh = th; s_cnlt = cnlt; }
        uint32_t n = NPIX - cnlt, t0 = cnlt;
        float nm1f = (float)n - 1.0f;
        int last = (int)nm1f;
        const float pp[3] = {0.25f, 0.5f, 0.75f};
        int np = 0;
        for (int qi = 0; qi < 3; ++qi) {
          float pos = pp[qi] * nm1f;
          float lof = floorf(pos);
          float fr = pos - lof;
          int lo_i = (int)lof;
          int hi_i = min(lo_i + 1, last);
          bool needB = (fr > 0.0f) && (hi_i != lo_i);
          if (lane == 0) { s_qfr[qi] = fr; s_qdup[qi] = needB ? 0 : 1; }
          {
            uint32_t r = t0 + (uint32_t)lo_i;
            int b = wfind2048(HC1, r, lane);
            uint32_t bw = b ? HC1[b - 1] : 0u;
            int sq = slotOf((uint32_t)b, s_ivLo, s_ivHi, s_ivS0, niv);
            if (sq >= 0) {
              const uint32_t* Pq = &L2H[sq * 256];
              int b2q = wfind256(Pq, r - bw, lane);
              float v = key2f(((uint32_t)b << 21) | ((uint32_t)b2q << 13));
              if (lane == 0) { s_qA[qi] = v; s_qB[qi] = v; }
            } else {
              if (lane == 0) { s_prank[np] = r; s_ptag[np] = (uint8_t)(qi * 2); s_pbin[np] = (uint32_t)b; }
              ++np;
            }
          }
          if (needB) {
            uint32_t r = t0 + (uint32_t)hi_i;
            int b = wfind2048(HC1, r, lane);
            uint32_t bw = b ? HC1[b - 1] : 0u;
            int sq = slotOf((uint32_t)b, s_ivLo, s_ivHi, s_ivS0, niv);
            if (sq >= 0) {
              const uint32_t* Pq = &L2H[sq * 256];
              int b2q = wfind256(Pq, r - bw, lane);
              float v = key2f(((uint32_t)b << 21) | ((uint32_t)b2q << 13));
              if (lane == 0) s_qB[qi] = v;
            } else {
              if (lane == 0) { s_prank[np] = r; s_ptag[np] = (uint8_t)(qi * 2 + 1); s_pbin[np] = (uint32_t)b; }
              ++np;
            }
          }
        }
        if (lane == 0) {
          s_npend = np;
          if (np > 0) plan_from_bins(np, s_pbin, s_ivLo, s_ivHi, s_ivS0, &s_niv, &s_nslots);
        }
      } else {
        int np = s_npend, newnp = 0;
        for (int i = 0; i < np; ++i) {
          uint32_t r = s_prank[i];
          int tg = s_ptag[i];
          int b = wfind2048(HC1, r, lane);
          uint32_t bw = b ? HC1[b - 1] : 0u;
          int sq = slotOf((uint32_t)b, s_ivLo, s_ivHi, s_ivS0, niv);
          if (sq >= 0) {
            const uint32_t* Pq = &L2H[sq * 256];
            int b2q = wfind256(Pq, r - bw, lane);
            float v = key2f(((uint32_t)b << 21) | ((uint32_t)b2q << 13));
            if (lane == 0) { if (tg & 1) s_qB[tg >> 1] = v; else s_qA[tg >> 1] = v; }
          } else {
            if (lane == 0) { s_prank[newnp] = r; s_ptag[newnp] = (uint8_t)tg; s_pbin[newnp] = (uint32_t)b; }
            ++newnp;
          }
        }
        if (lane == 0) {
          s_npend = newnp;
          if (newnp > 0) plan_from_bins(newnp, s_pbin, s_ivLo, s_ivHi, s_ivS0, &s_niv, &s_nslots);
        }
      }
    }
    __syncthreads();
    if (s_npend == 0) break;
    __syncthreads();
  }

  const float thresh = s_thresh;
  const uint32_t n = NPIX - s_cnlt;
  const float vmax  = key2f(smaxkey);
  const float vminf = thresh;

  // ---- Pass D (fused): masked moments, |x|, centroid, hist16, gradient ----
  // Each wave covers one full row per iteration (y = wid + 16t, wave-uniform);
  // horizontal neighbors come from intra-wave shuffles, no side loads.
  float rng = vmax - vminf;
  float denomf = (rng > 0.0f) ? rng : 1.0f;
  float sc16 = 16.0f / denomf;
  float sxl = 0, sx2l = 0, sx3l = 0, sx4l = 0, sabl = 0, sgl = 0, sg2l = 0;
  uint32_t syi = 0, sxi = 0;
#pragma unroll 4
  for (int t = 0; t < EPT4; ++t) {
    int i4 = tid + t * NTHREADS;
    float4 v = sl4[i4];
    float lf = __shfl_up(v.w, 1);     // left quad's w (lane-1), wave-uniform issue
    float rt = __shfl_down(v.x, 1);   // right quad's x (lane+1)
    bool m0 = v.x >= thresh, m1 = v.y >= thresh, m2 = v.z >= thresh, m3 = v.w >= thresh;
    if (m0 | m1 | m2 | m3) {
      int y = i4 >> 6;                // wave-uniform row
      float4 up = sl4[(y > 0)   ? (i4 - 64) : i4];
      float4 dn = sl4[(y < 255) ? (i4 + 64) : i4];
      float gy0, gy1, gy2, gy3;
      if (y == 0)        { gy0 = dn.x - v.x; gy1 = dn.y - v.y; gy2 = dn.z - v.z; gy3 = dn.w - v.w; }
      else if (y == 255) { gy0 = v.x - up.x; gy1 = v.y - up.y; gy2 = v.z - up.z; gy3 = v.w - up.w; }
      else { gy0 = 0.5f * (dn.x - up.x); gy1 = 0.5f * (dn.y - up.y);
             gy2 = 0.5f * (dn.z - up.z); gy3 = 0.5f * (dn.w - up.w); }
      float gx0 = (lane == 0)  ? (v.y - v.x) : 0.5f * (v.y - lf);
      float gx1 = 0.5f * (v.z - v.x);
      float gx2 = 0.5f * (v.w - v.y);
      float gx3 = (lane == 63) ? (v.w - v.z) : 0.5f * (rt - v.z);
#define DOC(mc, vc, gyc, gxc, xc)                                              \
      if (mc) {                                                                \
        float gm = sqrtf((gyc) * (gyc) + (gxc) * (gxc));                       \
        sgl += gm; sg2l += gm * gm;                                            \
        float v2 = (vc) * (vc);                                                \
        sxl += (vc); sx2l += v2; sx3l += v2 * (vc); sx4l += v2 * v2;           \
        sabl += fabsf(vc);                                                     \
        syi += (uint32_t)y; sxi += (uint32_t)((lane << 2) + (xc));             \
        float bf = floorf(((vc) - vminf) * sc16);                              \
        int bin = (int)bf; bin = bin < 0 ? 0 : (bin > 15 ? 15 : bin);          \
        atomicAdd(&H16[(wid << 4) + bin], 1u);                                 \
      }
      DOC(m0, v.x, gy0, gx0, 0)
      DOC(m1, v.y, gy1, gx1, 1)
      DOC(m2, v.z, gy2, gx2, 2)
      DOC(m3, v.w, gy3, gx3, 3)
#undef DOC
    }
  }

  // ---- 9-way reduction: f32/u32 wave shuffles, f64 only across 16 waves ----
  {
    float af[7] = {sxl, sx2l, sx3l, sx4l, sabl, sgl, sg2l};
#pragma unroll
    for (int k = 0; k < 7; ++k)
      for (int d = 32; d > 0; d >>= 1) af[k] += __shfl_down(af[k], d);
    uint32_t au0 = syi, au1 = sxi;
    for (int d = 32; d > 0; d >>= 1) { au0 += __shfl_down(au0, d); au1 += __shfl_down(au1, d); }
    if (lane == 0) {
#pragma unroll
      for (int k = 0; k < 7; ++k) tmpD9[wid * 9 + k] = (double)af[k];
      tmpD9[wid * 9 + 7] = (double)au0;
      tmpD9[wid * 9 + 8] = (double)au1;
    }
  }
  __syncthreads();
  if (tid < 64) {
    double r0 = 0, r1 = 0, r2 = 0, r3 = 0, r4 = 0, r5 = 0, r6 = 0, r7 = 0, r8 = 0;
    if (lane < 16) {
      r0 = tmpD9[lane * 9 + 0]; r1 = tmpD9[lane * 9 + 1]; r2 = tmpD9[lane * 9 + 2];
      r3 = tmpD9[lane * 9 + 3]; r4 = tmpD9[lane * 9 + 4]; r5 = tmpD9[lane * 9 + 5];
      r6 = tmpD9[lane * 9 + 6]; r7 = tmpD9[lane * 9 + 7]; r8 = tmpD9[lane * 9 + 8];
    }
    for (int d = 8; d > 0; d >>= 1) {
      r0 += __shfl_down(r0, d); r1 += __shfl_down(r1, d); r2 += __shfl_down(r2, d);
      r3 += __shfl_down(r3, d); r4 += __shfl_down(r4, d); r5 += __shfl_down(r5, d);
      r6 += __shfl_down(r6, d); r7 += __shfl_down(r7, d); r8 += __shfl_down(r8, d);
    }
    if (lane == 0) {
      s_red[0] = r0; s_red[1] = r1; s_red[2] = r2; s_red[3] = r3; s_red[4] = r4;
      s_red[5] = r5; s_red[6] = r6; s_red[7] = r7; s_red[8] = r8;
    }
  }
  __syncthreads();

  // ---- finalize features (thread 0) ----
  if (tid == 0) {
    double sx = s_red[0], sx2 = s_red[1], sx3 = s_red[2], sx4 = s_red[3];
    double sab = s_red[4], sg = s_red[5], sg2 = s_red[6], syid = s_red[7], sxid = s_red[8];
    double dn = (double)n;
    double mean = sx / dn;
    double M2 = sx2 - sx * sx / dn;
    double std_ = sqrt(M2 / dn);
    double se = fmax(std_, 1e-6);
    double S3 = sx3 - 3.0 * mean * sx2 + 2.0 * dn * mean * mean * mean;
    double S4 = sx4 - 4.0 * mean * sx3 + 6.0 * mean * mean * sx2
                - 3.0 * dn * mean * mean * mean * mean;
    double skew = (S3 / dn) / (se * se * se);
    skew = fmin(fmax(skew, -50.0), 50.0);
    double kurt = (S4 / dn) / (se * se * se * se);
    kurt = fmin(fmax(kurt, 0.0), 100.0);
    double msq = sx2 / dn;
    double absmean = sab / dn;

    double ent = 0.0;
    double nden = fmax(dn, 1.0);
    for (int bi = 0; bi < 16; ++bi) {
      uint32_t hb = 0;
#pragma unroll
      for (int w = 0; w < 16; ++w) hb += H16[(w << 4) + bi];
      double p = fmax((double)hb / nden, 1e-6);
      ent -= p * log(p);
    }
    if (fabsf(vminf - vmax) <= 1e-8f + 1e-5f * fabsf(vmax)) ent = 0.0;

    double gmean = sg / dn;
    double gstd = sqrt(fmax(sg2 / dn - gmean * gmean, 0.0));
    double cy = (syid / dn) / 255.0;
    double cx = (sxid / dn) / 255.0;
    double frac = dn / (double)NPIX;

    float qv[3];
#pragma unroll
    for (int qi = 0; qi < 3; ++qi) {
      float A = s_qA[qi];
      float Bv = s_qdup[qi] ? A : s_qB[qi];
      float fr = s_qfr[qi];
      qv[qi] = A * (1.0f - fr) + Bv * fr;
    }

    float* fo = feats + (size_t)blockIdx.x * NFEAT;
    fo[0]  = (float)mean;  fo[1]  = (float)std_;  fo[2]  = vminf;       fo[3]  = vmax;
    fo[4]  = qv[0];        fo[5]  = qv[1];        fo[6]  = qv[2];       fo[7]  = (float)msq;
    fo[8]  = (float)ent;   fo[9]  = (float)skew;  fo[10] = (float)kurt; fo[11] = (float)frac;
    fo[12] = (float)gmean; fo[13] = (float)gstd;  fo[14] = (float)cy;   fo[15] = (float)cx;
    fo[16] = (float)frac;  fo[17] = (float)absmean;
  }
}

__global__ __launch_bounds__(EMB) void token_kernel(const float* __restrict__ feats,
                                                    const float* __restrict__ W,
                                                    const float* __restrict__ b,
                                                    const float* __restrict__ gamma,
                                                    const float* __restrict__ beta,
                                                    float* __restrict__ out,
                                                    float* __restrict__ maskout) {
  __shared__ float f[NFEAT];
  __shared__ float red[4];
  int s = blockIdx.x, e = threadIdx.x;
  if (e < NFEAT) f[e] = feats[(size_t)s * NFEAT + e];
  __syncthreads();
  float acc = b[e];
#pragma unroll
  for (int k = 0; k < NFEAT; ++k) acc += f[k] * W[k * EMB + e];
  int lane = e & 63, wd = e >> 6;
  float sum = acc;
  for (int d = 32; d > 0; d >>= 1) sum += __shfl_down(sum, d);
  if (lane == 0) red[wd] = sum;
  __syncthreads();
  float mu = (red[0] + red[1] + red[2] + red[3]) * (1.0f / EMB);
  float c = acc - mu;
  float s2 = c * c;
  for (int d = 32; d > 0; d >>= 1) s2 += __shfl_down(s2, d);
  __syncthreads();
  if (lane == 0) red[wd] = s2;
  __syncthreads();
  float var = (red[0] + red[1] + red[2] + red[3]) * (1.0f / EMB);
  float o = c / sqrtf(var + 1e-5f) * gamma[e] + beta[e];
  out[(size_t)s * EMB + e] = o;
  if (e == 0) maskout[s] = 0.0f;
}

extern "C" void kernel_launch(void* const* d_in, const int* in_sizes, int n_in,
                              void* d_out, int out_size, void* d_ws, size_t ws_size,
                              hipStream_t stream) {
  const float* vol   = (const float*)d_in[0];
  const float* W     = (const float*)d_in[1];
  const float* b     = (const float*)d_in[2];
  const float* gamma = (const float*)d_in[3];
  const float* beta  = (const float*)d_in[4];
  float* out = (float*)d_out;
  float* feats = (float*)d_ws;

  feat_kernel<<<NSLICES, NTHREADS, 0, stream>>>(vol, feats);
  token_kernel<<<NSLICES, EMB, 0, stream>>>(feats, W, b, gamma, beta,
                                            out, out + (size_t)NSLICES * EMB);
}